// Round 1
// baseline (435.428 us; speedup 1.0000x reference)
//
#include <hip/hip_runtime.h>
#include <hip/hip_bf16.h>
#include <stdint.h>

// ---- problem constants ----
#define M_ROWS   224        // B*N = 32*7
#define K_DIM    49152      // D_MODEL*PATCH_NUMS
#define NCOL     1344       // 4 bands * 336
#define PRED     336
#define S_CHUNKS 36         // split-K chunks: 21*36 = 756 blocks ~= 3/CU
#define KSTEPS   1536       // K_DIM / 32
#define LDA      40         // LDS row stride in shorts (32 + 8 pad) -> conflict-free b128

typedef __attribute__((ext_vector_type(8))) short short8;
typedef __attribute__((ext_vector_type(4))) short short4_t;
typedef __attribute__((ext_vector_type(4))) float floatx4;

__device__ __forceinline__ uint16_t f32_to_bf16(float f) {
    uint32_t u = __builtin_bit_cast(uint32_t, f);
    uint32_t r = (u + 0x7fffu + ((u >> 16) & 1u)) >> 16;   // RNE
    return (uint16_t)r;
}
__device__ __forceinline__ float bf16_to_f32(uint16_t h) {
    uint32_t u = ((uint32_t)h) << 16;
    return __builtin_bit_cast(float, u);
}

// ======================= Kernel 1: split-K GEMM (bf16 MFMA) =======================
// grid: (21 col-tiles, 36 k-chunks), block: 256 (4 waves x 16 cols, full M=224)
// Writes bf16 partials P[m][s][col], each slot written by exactly one block.
__global__ __launch_bounds__(256, 3) void gemm_partial(
    const float* __restrict__ X,      // (224, 49152)
    const float* __restrict__ W,      // (4, 49152, 336)
    uint16_t* __restrict__ P)         // (224, 36, 1344) bf16
{
    __shared__ uint16_t lA[M_ROWS * LDA];    // 17.9 KB

    const int ct   = blockIdx.x;             // 0..20
    const int s    = blockIdx.y;             // 0..35
    const int tid  = threadIdx.x;
    const int lane = tid & 63;
    const int w    = tid >> 6;               // wave 0..3
    const int c0w  = ct * 64 + w * 16;       // wave's first flat column
    const int band = c0w / PRED;             // 16 | 336 -> no band straddle per wave
    const int p0   = c0w - band * PRED;
    const int l15  = lane & 15;              // n (col) within tile / m within A-frag
    const int kq   = lane >> 4;              // k-subgroup 0..3 (8 k's each)

    // Per-lane W base: element W[band][k][p0+l15], with kq*8 k-offset folded in.
    const float* wbase = W + (size_t)band * ((size_t)K_DIM * PRED)
                           + (size_t)(kq * 8) * PRED
                           + (size_t)(p0 + l15);

    const int step_begin = (s * KSTEPS) / S_CHUNKS;
    const int step_end   = ((s + 1) * KSTEPS) / S_CHUNKS;

    floatx4 acc[14];
    #pragma unroll
    for (int f = 0; f < 14; ++f) acc[f] = (floatx4){0.f, 0.f, 0.f, 0.f};

    for (int st = step_begin; st < step_end; ++st) {
        const int k0 = st * 32;

        // --- W fragment: 8 strided dword loads (64B segments), issued early ---
        const float* wp = wbase + (size_t)k0 * PRED;
        float bf[8];
        #pragma unroll
        for (int j = 0; j < 8; ++j) bf[j] = wp[(size_t)j * PRED];

        __syncthreads();   // previous iteration's LDS frag reads complete

        // --- stage A chunk (224 rows x 32 k) fp32 -> bf16 into LDS ---
        // 1792 float4 pieces over 256 threads * 7: lanes 0..7 cover one 128B row-chunk.
        #pragma unroll
        for (int r = 0; r < 7; ++r) {
            const int i     = tid + 256 * r;       // 0..1791
            const int m     = i >> 3;
            const int piece = i & 7;
            const float4 v = *((const float4*)(X + (size_t)m * K_DIM + k0) + piece);
            short4_t pk;
            pk.x = (short)f32_to_bf16(v.x);
            pk.y = (short)f32_to_bf16(v.y);
            pk.z = (short)f32_to_bf16(v.z);
            pk.w = (short)f32_to_bf16(v.w);
            *(short4_t*)&lA[m * LDA + piece * 4] = pk;   // b64 writes, near-uniform banks
        }
        __syncthreads();

        // --- pack B fragment (8 consecutive k for this lane's column) ---
        short8 bfrag;
        #pragma unroll
        for (int j = 0; j < 4; ++j) {
            ((uint32_t*)&bfrag)[j] =
                (uint32_t)f32_to_bf16(bf[2 * j]) | ((uint32_t)f32_to_bf16(bf[2 * j + 1]) << 16);
        }

        // --- 14 MFMAs: full M per wave ---
        #pragma unroll
        for (int f = 0; f < 14; ++f) {
            // A-frag: m = 16f + (lane&15), k = kq*8 + j  (16B aligned: 80*m + 16*kq)
            short8 afrag = *(const short8*)&lA[(16 * f + l15) * LDA + kq * 8];
            acc[f] = __builtin_amdgcn_mfma_f32_16x16x32_bf16(afrag, bfrag, acc[f], 0, 0, 0);
        }
    }

    // --- write bf16 partials: C/D layout col=lane&15, row=kq*4+reg ---
    const int col = c0w + l15;
    #pragma unroll
    for (int f = 0; f < 14; ++f) {
        #pragma unroll
        for (int r = 0; r < 4; ++r) {
            const int m = 16 * f + kq * 4 + r;
            P[((size_t)m * S_CHUNKS + s) * NCOL + col] = f32_to_bf16(acc[f][r]);
        }
    }
}

// ======================= Kernel 2: partial reduce + bias + iSWT =======================
// db4 reconstruction filters (pywt convention), REC_LO = reverse(DEC_LO), REC_HI QMF.
__device__ const float REC_LO[8] = {
     0.23037781330885523f,  0.7148465705525415f,   0.6308807679295904f,
    -0.02798376941698385f, -0.18703481171888114f,  0.030841381835986965f,
     0.032883011666982945f, -0.010597401784997278f };
__device__ const float REC_HI[8] = {
     0.010597401784997278f, 0.032883011666982945f, -0.030841381835986965f,
    -0.18703481171888114f,  0.02798376941698385f,   0.6308807679295904f,
    -0.7148465705525415f,   0.23037781330885523f };

__global__ __launch_bounds__(256) void reduce_iswt(
    const uint16_t* __restrict__ P,    // (224, 36, 1344) bf16
    const float* __restrict__ bias,    // (4, 336) -> flat index == flat col
    float* __restrict__ out)           // (224, 336)
{
    __shared__ float coeff[NCOL];
    __shared__ float buf[2][PRED];

    const int row = blockIdx.x;
    const int tid = threadIdx.x;
    const uint16_t* pr = P + (size_t)row * S_CHUNKS * NCOL;

    // sum split-K partials + bias  (contiguous, coalesced)
    for (int c = tid; c < NCOL; c += 256) {
        float a = bias[c];
        for (int s = 0; s < S_CHUNKS; ++s) a += bf16_to_f32(pr[s * NCOL + c]);
        coeff[c] = a;
    }
    __syncthreads();

    for (int t = tid; t < PRED; t += 256) buf[0][t] = coeff[t];   // band 0 = cA
    __syncthreads();

    int curb = 0;
    for (int j = 3; j >= 1; --j) {
        const int step = 1 << (j - 1);           // 4, 2, 1
        const int M    = PRED / step;            // 84, 168, 336
        const float* cd  = &coeff[(4 - j) * PRED];  // cD3, cD2, cD1
        const float* cur = buf[curb];
        float* nxt       = buf[curb ^ 1];
        for (int t = tid; t < PRED; t += 256) {
            const int s = t & (step - 1);
            const int m = t / step;
            const int mm1 = (m == 0) ? (M - 1) : (m - 1);
            float x1 = 0.f, x2 = 0.f;
            #pragma unroll
            for (int k = 0; k < 8; ++k) {
                int i1 = m + 3 - k;  if (i1 < 0) i1 += M; else if (i1 >= M) i1 -= M;
                if ((i1 & 1) == 0) {                     // even index of upsampled seq
                    const int pos = i1 * step + s;       // even-m subsequence element
                    x1 += cur[pos] * REC_LO[k] + cd[pos] * REC_HI[k];
                }
                int i2 = mm1 + 3 - k;  if (i2 < 0) i2 += M; else if (i2 >= M) i2 -= M;
                if ((i2 & 1) == 0) {
                    const int pos = (i2 + 1) * step + s; // odd-m subsequence element
                    x2 += cur[pos] * REC_LO[k] + cd[pos] * REC_HI[k];
                }
            }
            nxt[t] = 0.5f * (x1 + x2);
        }
        __syncthreads();
        curb ^= 1;
    }

    for (int t = tid; t < PRED; t += 256) out[(size_t)row * PRED + t] = buf[curb][t];
}

// ======================= launch =======================
extern "C" void kernel_launch(void* const* d_in, const int* in_sizes, int n_in,
                              void* d_out, int out_size, void* d_ws, size_t ws_size,
                              hipStream_t stream) {
    const float* X    = (const float*)d_in[0];   // (32,7,768,64) = (224, 49152)
    const float* W    = (const float*)d_in[1];   // (4, 49152, 336)
    const float* bias = (const float*)d_in[2];   // (4, 336)
    float* out        = (float*)d_out;           // (224, 336)
    uint16_t* P       = (uint16_t*)d_ws;         // 224*36*1344*2 = 21.7 MB partials

    gemm_partial<<<dim3(21, S_CHUNKS), 256, 0, stream>>>(X, W, P);
    reduce_iswt<<<M_ROWS, 256, 0, stream>>>(P, bias, out);
}